// Round 14
// baseline (78.194 us; speedup 1.0000x reference)
//
#include <hip/hip_runtime.h>

// ---------------------------------------------------------------------------
// MixModel, 3 thread-segments/row, persistent blocks + double-buffered DMA.
// Ladder: R1 136VGPR 127 | R2-R4 spill ~157 | R6 76 | R7 pk 74.8 | R8 85
//   R9 gridstride(VGPR68) 94.8 | R10 LDS-DMA 64-row tile 71.1us (best)
//   R11 2tiles 94.9 (bloat) | R12 wave-private 86.8 (bloat) | R13 384thr 75.7
// R14 = R10 body, unchanged, + persistent 2048x192 grid, 2 LDS tile buffers:
//   per tile: issue DMA(next->buf^1) FIRST, s_waitcnt vmcnt(3) (current
//   tile's 3 loads done; next's 3 stay in flight across the barrier — T4
//   counted-vmcnt, never drain to 0 mid-loop), raw s_barrier, compute,
//   s_barrier (WAR protect), flip. Prefetch costs 0 VGPR (DMA direct to LDS)
//   — the R9 register blowup can't recur. One full drain in prologue only.
// Spill signature: WRITE_SIZE >> 140,625 KB.
// ---------------------------------------------------------------------------

typedef float f2 __attribute__((ext_vector_type(2)));

__device__ __forceinline__ f2 splat2(float x) { f2 v; v.x = x; v.y = x; return v; }
__device__ __forceinline__ f2 mk2(float a, float b) { f2 v; v.x = a; v.y = b; return v; }
__device__ __forceinline__ f2 fma2(f2 a, f2 b, f2 c) { return __builtin_elementwise_fma(a, b, c); }
__device__ __forceinline__ f2 relu2(f2 a) { return __builtin_elementwise_max(a, splat2(0.0f)); }

// Packed MLP 3->3->6->3 for a pair of positions.
__device__ __forceinline__ void mlp_a2(f2 x0, f2 x1, f2 x2,
                                       const float* __restrict__ w0, const float* __restrict__ b0,
                                       const float* __restrict__ w1, const float* __restrict__ b1,
                                       const float* __restrict__ w2, const float* __restrict__ b2,
                                       f2& o0, f2& o1, f2& o2)
{
    f2 h0[3];
#pragma unroll
    for (int q = 0; q < 3; ++q) {
        f2 a = fma2(x0, splat2(w0[q*3+0]), splat2(b0[q]));
        a = fma2(x1, splat2(w0[q*3+1]), a);
        a = fma2(x2, splat2(w0[q*3+2]), a);
        h0[q] = relu2(a);
    }
    f2 h1[6];
#pragma unroll
    for (int q = 0; q < 6; ++q) {
        f2 a = fma2(h0[0], splat2(w1[q*3+0]), splat2(b1[q]));
        a = fma2(h0[1], splat2(w1[q*3+1]), a);
        a = fma2(h0[2], splat2(w1[q*3+2]), a);
        h1[q] = relu2(a);
    }
    f2 t[3];
#pragma unroll
    for (int q = 0; q < 3; ++q) {
        f2 a = fma2(h1[0], splat2(w2[q*6+0]), splat2(b2[q]));
#pragma unroll
        for (int i = 1; i < 6; ++i) a = fma2(h1[i], splat2(w2[q*6+i]), a);
        t[q] = a;
    }
    o0 = t[0]; o1 = t[1]; o2 = t[2];
}

// Packed MLP 4->4->6->2 for a pair of positions.
__device__ __forceinline__ void mlp_b2(f2 x0, f2 x1, f2 x2, f2 x3,
                                       const float* __restrict__ w0, const float* __restrict__ b0,
                                       const float* __restrict__ w1, const float* __restrict__ b1,
                                       const float* __restrict__ w2, const float* __restrict__ b2,
                                       f2& o0, f2& o1)
{
    f2 h0[4];
#pragma unroll
    for (int q = 0; q < 4; ++q) {
        f2 a = fma2(x0, splat2(w0[q*4+0]), splat2(b0[q]));
        a = fma2(x1, splat2(w0[q*4+1]), a);
        a = fma2(x2, splat2(w0[q*4+2]), a);
        a = fma2(x3, splat2(w0[q*4+3]), a);
        h0[q] = relu2(a);
    }
    f2 h1[6];
#pragma unroll
    for (int q = 0; q < 6; ++q) {
        f2 a = fma2(h0[0], splat2(w1[q*4+0]), splat2(b1[q]));
        a = fma2(h0[1], splat2(w1[q*4+1]), a);
        a = fma2(h0[2], splat2(w1[q*4+2]), a);
        a = fma2(h0[3], splat2(w1[q*4+3]), a);
        h1[q] = relu2(a);
    }
    f2 t[2];
#pragma unroll
    for (int q = 0; q < 2; ++q) {
        f2 a = fma2(h1[0], splat2(w2[q*6+0]), splat2(b2[q]));
#pragma unroll
        for (int i = 1; i < 6; ++i) a = fma2(h1[i], splat2(w2[q*6+i]), a);
        t[q] = a;
    }
    o0 = t[0]; o1 = t[1];
}

// One (row-in-tile, r) segment: window from LDS tile, compute, store 12 cols.
__device__ __forceinline__ void seg_compute(
    const float4* s4t, const float* sreg, int rl, int r,
    const float* __restrict__ w10, const float* __restrict__ b10,
    const float* __restrict__ w11, const float* __restrict__ b11,
    const float* __restrict__ w12, const float* __restrict__ b12,
    const float* __restrict__ w20, const float* __restrict__ b20,
    const float* __restrict__ w21, const float* __restrict__ b21,
    const float* __restrict__ w22, const float* __restrict__ b22,
    const float* __restrict__ w30, const float* __restrict__ b30,
    const float* __restrict__ w31, const float* __restrict__ b31,
    const float* __restrict__ w32, const float* __restrict__ b32,
    float4* __restrict__ o4)
{
    // ---- 20-col window: W(k) = u[row, (12r+k) mod 36], k=-4..15 ----
    float w_[20];
#pragma unroll
    for (int t = 0; t < 5; ++t) {
        int idx = 3 * r + 8 + t;               // 8..18
        if (idx >= 9) idx -= 9;                // 0..9
        if (idx >= 9) idx -= 9;                // 0..8 (double wrap)
        const float4 v = s4t[rl * 9 + idx];
        w_[4*t+0] = v.x; w_[4*t+1] = v.y; w_[4*t+2] = v.z; w_[4*t+3] = v.w;
    }
#define W(k) w_[(k) + 4]

    const f2 r02 = splat2(sreg[0]);
    const float* rb = sreg + 12 * r;

    f2 c0[2], c1[2], c2[2];   // pair P covers jj = 2P, 2P+1

#pragma unroll
    for (int P = 0; P < 2; ++P) {
        const int q = 6 * P;
        f2 a0, a1, a2;
        mlp_a2(mk2(W(q - 2), W(q + 1)), mk2(W(q), W(q + 3)), mk2(W(q + 1), W(q + 4)),
               w10, b10, w11, b11, w12, b12, a0, a1, a2);
        const f2 ua = mk2(W(q - 1), W(q + 2));
        const f2 ub = mk2(W(q + 2), W(q + 5));
        const f2 rv = mk2(rb[q + 1], rb[q + 4]);
        const f2 uv = mk2(W(q), W(q + 3));
        c0[P] = fma2(uv, rv, r02) + fma2(a2, ub, fma2(a1, ua, a0));
    }
#pragma unroll
    for (int P = 0; P < 2; ++P) {
        const int q = 6 * P;
        f2 a0, a1, a2;
        mlp_a2(mk2(W(q), W(q + 3)), mk2(W(q + 1), W(q + 4)), mk2(W(q + 3), W(q + 6)),
               w20, b20, w21, b21, w22, b22, a0, a1, a2);
        const f2 ua = mk2(W(q - 1), W(q + 2));
        const f2 ub = mk2(W(q + 2), W(q + 5));
        const f2 rv = mk2(rb[q + 2], rb[q + 5]);
        const f2 uv = mk2(W(q + 1), W(q + 4));
        c1[P] = fma2(uv, rv, r02) + fma2(a2, ub, fma2(a1, ua, a0));
    }
#pragma unroll
    for (int P = 0; P < 2; ++P) {
        const int q = 6 * P;
        f2 d0, d1;
        mlp_b2(mk2(W(q), W(q + 3)), mk2(W(q + 1), W(q + 4)),
               mk2(W(q + 3), W(q + 6)), mk2(W(q + 4), W(q + 7)),
               w30, b30, w31, b31, w32, b32, d0, d1);
        const f2 ub = mk2(W(q + 2), W(q + 5));
        const f2 rv = mk2(rb[q + 3], rb[q + 6]);
        c2[P] = fma2(ub, rv, r02) + fma2(d1, ub, d0);
    }
#undef W

    o4[0] = make_float4(c0[0].x, c1[0].x, c2[0].x, c0[0].y);
    o4[1] = make_float4(c1[0].y, c2[0].y, c0[1].x, c1[1].x);
    o4[2] = make_float4(c2[1].x, c0[1].y, c1[1].y, c2[1].y);
}

#define TPB 192           // 3 waves; 64-row tile = 576 f4 = 3 insts/thread
#define NBLK 2048

__global__ __launch_bounds__(TPB) void mixmodel_kernel(
    const float* __restrict__ u, const float* __restrict__ reg,
    const float* __restrict__ w10, const float* __restrict__ b10,
    const float* __restrict__ w11, const float* __restrict__ b11,
    const float* __restrict__ w12, const float* __restrict__ b12,
    const float* __restrict__ w20, const float* __restrict__ b20,
    const float* __restrict__ w21, const float* __restrict__ b21,
    const float* __restrict__ w22, const float* __restrict__ b22,
    const float* __restrict__ w30, const float* __restrict__ b30,
    const float* __restrict__ w31, const float* __restrict__ b31,
    const float* __restrict__ w32, const float* __restrict__ b32,
    float* __restrict__ out, int ntiles)
{
    __shared__ float4 s4[2 * 576];       // double-buffered 9216-B tiles
    __shared__ float  sreg[37];

    const int wid  = threadIdx.x >> 6;
    const int lane = threadIdx.x & 63;
    const int G    = NBLK;               // tile stride

    int tile = blockIdx.x;
    if (tile >= ntiles) return;

    // ---- prologue: sreg + first tile DMA, one full drain ----
    if (threadIdx.x < 37) sreg[threadIdx.x] = reg[threadIdx.x];
    {
        const float4* g = reinterpret_cast<const float4*>(u) + (size_t)tile * 576;
#pragma unroll
        for (int k = 0; k < 3; ++k) {
            const int base = k * TPB + wid * 64;
            __builtin_amdgcn_global_load_lds(
                (const __attribute__((address_space(1))) void*)(g + base + lane),
                (__attribute__((address_space(3))) void*)(s4 + base),
                16, 0, 0);
        }
    }
    __syncthreads();                     // full drain, once

    const int rl = threadIdx.x / 3;      // row within tile, 0..63
    const int r  = threadIdx.x - 3 * rl; // 0..2 -> output cols 12r..12r+11

    int buf = 0;
    while (true) {
        const int next = tile + G;
        const bool has_next = next < ntiles;   // block-uniform

        if (has_next) {
            // issue next tile's DMA into the other buffer (0 VGPR cost)
            const float4* g = reinterpret_cast<const float4*>(u) + (size_t)next * 576;
            float4* const dst = s4 + (buf ^ 1) * 576;
#pragma unroll
            for (int k = 0; k < 3; ++k) {
                const int base = k * TPB + wid * 64;
                __builtin_amdgcn_global_load_lds(
                    (const __attribute__((address_space(1))) void*)(g + base + lane),
                    (__attribute__((address_space(3))) void*)(dst + base),
                    16, 0, 0);
            }
            // wait only the CURRENT tile's 3 loads; next's 3 stay in flight
            asm volatile("s_waitcnt vmcnt(3)" ::: "memory");
        } else {
            asm volatile("s_waitcnt vmcnt(0)" ::: "memory");
        }
        __builtin_amdgcn_s_barrier();          // current tile fully in LDS
        __builtin_amdgcn_sched_barrier(0);

        seg_compute(s4 + buf * 576, sreg, rl, r,
                    w10, b10, w11, b11, w12, b12,
                    w20, b20, w21, b21, w22, b22,
                    w30, b30, w31, b31, w32, b32,
                    reinterpret_cast<float4*>(out + (size_t)(tile * 64 + rl) * 36 + 12 * r));

        if (!has_next) break;
        __builtin_amdgcn_s_barrier();          // all waves done reading buf
        __builtin_amdgcn_sched_barrier(0);
        tile = next;
        buf ^= 1;
    }
}

extern "C" void kernel_launch(void* const* d_in, const int* in_sizes, int n_in,
                              void* d_out, int out_size, void* d_ws, size_t ws_size,
                              hipStream_t stream)
{
    const float* u   = (const float*)d_in[1];
    const float* reg = (const float*)d_in[2];
    const float* w10 = (const float*)d_in[3];
    const float* b10 = (const float*)d_in[4];
    const float* w11 = (const float*)d_in[5];
    const float* b11 = (const float*)d_in[6];
    const float* w12 = (const float*)d_in[7];
    const float* b12 = (const float*)d_in[8];
    const float* w20 = (const float*)d_in[9];
    const float* b20 = (const float*)d_in[10];
    const float* w21 = (const float*)d_in[11];
    const float* b21 = (const float*)d_in[12];
    const float* w22 = (const float*)d_in[13];
    const float* b22 = (const float*)d_in[14];
    const float* w30 = (const float*)d_in[15];
    const float* b30 = (const float*)d_in[16];
    const float* w31 = (const float*)d_in[17];
    const float* b31 = (const float*)d_in[18];
    const float* w32 = (const float*)d_in[19];
    const float* b32 = (const float*)d_in[20];
    float* out = (float*)d_out;

    const int n = in_sizes[1] / 36;      // 1,000,000 rows; 64 | n exactly
    const int ntiles = n / 64;           // 15625

    hipLaunchKernelGGL(mixmodel_kernel, dim3(NBLK), dim3(TPB), 0, stream,
                       u, reg, w10, b10, w11, b11, w12, b12,
                       w20, b20, w21, b21, w22, b22,
                       w30, b30, w31, b31, w32, b32, out, ntiles);
}

// Round 16
// 65.256 us; speedup vs baseline: 1.1983x; 1.1983x over previous
//
#include <hip/hip_runtime.h>

// ---------------------------------------------------------------------------
// MixModel, 3 thread-segments/row, LDS-staged u-tile (R10) + NT stores.
// Ladder: R1 136VGPR 127 | R2-R4 spill ~157 | R6 76 | R7 pk 74.8 | R8 85
//   R9 94.8 | R10 LDS-DMA 64-row tile 71.1us (best) | R11 94.9 | R12 86.8
//   R13 384thr 75.7 | R14 persistent+dbuf 78.2 | R15 compile fail (builtin
//   rejects HIP_vector_type float4 — use clang ext_vector_type instead).
// R16 = R15 with ext_vector float4 for the NT stores: out (144MB) is
//   write-once-never-read -> don't allocate it in L2/L3. u(144MB)+out(144MB)
//   = 288MB > 256MiB L3, so the write stream evicts u (FETCH=70MB re-read).
//   NT stores keep u L3-resident: fetch ->~0, load latency drops.
// Spill signature: WRITE_SIZE >> 140,625 KB.
// ---------------------------------------------------------------------------

typedef float f2 __attribute__((ext_vector_type(2)));
typedef float fv4 __attribute__((ext_vector_type(4)));

__device__ __forceinline__ f2 splat2(float x) { f2 v; v.x = x; v.y = x; return v; }
__device__ __forceinline__ f2 mk2(float a, float b) { f2 v; v.x = a; v.y = b; return v; }
__device__ __forceinline__ f2 fma2(f2 a, f2 b, f2 c) { return __builtin_elementwise_fma(a, b, c); }
__device__ __forceinline__ f2 relu2(f2 a) { return __builtin_elementwise_max(a, splat2(0.0f)); }
__device__ __forceinline__ fv4 mk4(float a, float b, float c, float d)
{ fv4 v; v.x = a; v.y = b; v.z = c; v.w = d; return v; }

// Packed MLP 3->3->6->3 for a pair of positions.
__device__ __forceinline__ void mlp_a2(f2 x0, f2 x1, f2 x2,
                                       const float* __restrict__ w0, const float* __restrict__ b0,
                                       const float* __restrict__ w1, const float* __restrict__ b1,
                                       const float* __restrict__ w2, const float* __restrict__ b2,
                                       f2& o0, f2& o1, f2& o2)
{
    f2 h0[3];
#pragma unroll
    for (int q = 0; q < 3; ++q) {
        f2 a = fma2(x0, splat2(w0[q*3+0]), splat2(b0[q]));
        a = fma2(x1, splat2(w0[q*3+1]), a);
        a = fma2(x2, splat2(w0[q*3+2]), a);
        h0[q] = relu2(a);
    }
    f2 h1[6];
#pragma unroll
    for (int q = 0; q < 6; ++q) {
        f2 a = fma2(h0[0], splat2(w1[q*3+0]), splat2(b1[q]));
        a = fma2(h0[1], splat2(w1[q*3+1]), a);
        a = fma2(h0[2], splat2(w1[q*3+2]), a);
        h1[q] = relu2(a);
    }
    f2 t[3];
#pragma unroll
    for (int q = 0; q < 3; ++q) {
        f2 a = fma2(h1[0], splat2(w2[q*6+0]), splat2(b2[q]));
#pragma unroll
        for (int i = 1; i < 6; ++i) a = fma2(h1[i], splat2(w2[q*6+i]), a);
        t[q] = a;
    }
    o0 = t[0]; o1 = t[1]; o2 = t[2];
}

// Packed MLP 4->4->6->2 for a pair of positions.
__device__ __forceinline__ void mlp_b2(f2 x0, f2 x1, f2 x2, f2 x3,
                                       const float* __restrict__ w0, const float* __restrict__ b0,
                                       const float* __restrict__ w1, const float* __restrict__ b1,
                                       const float* __restrict__ w2, const float* __restrict__ b2,
                                       f2& o0, f2& o1)
{
    f2 h0[4];
#pragma unroll
    for (int q = 0; q < 4; ++q) {
        f2 a = fma2(x0, splat2(w0[q*4+0]), splat2(b0[q]));
        a = fma2(x1, splat2(w0[q*4+1]), a);
        a = fma2(x2, splat2(w0[q*4+2]), a);
        a = fma2(x3, splat2(w0[q*4+3]), a);
        h0[q] = relu2(a);
    }
    f2 h1[6];
#pragma unroll
    for (int q = 0; q < 6; ++q) {
        f2 a = fma2(h0[0], splat2(w1[q*4+0]), splat2(b1[q]));
        a = fma2(h0[1], splat2(w1[q*4+1]), a);
        a = fma2(h0[2], splat2(w1[q*4+2]), a);
        a = fma2(h0[3], splat2(w1[q*4+3]), a);
        h1[q] = relu2(a);
    }
    f2 t[2];
#pragma unroll
    for (int q = 0; q < 2; ++q) {
        f2 a = fma2(h1[0], splat2(w2[q*6+0]), splat2(b2[q]));
#pragma unroll
        for (int i = 1; i < 6; ++i) a = fma2(h1[i], splat2(w2[q*6+i]), a);
        t[q] = a;
    }
    o0 = t[0]; o1 = t[1];
}

#define ROWS_PB 64
#define TPB 192   // 3 waves; ROWS_PB*9 f4 chunks = 576 = 3*TPB

__global__ __launch_bounds__(TPB) void mixmodel_kernel(
    const float* __restrict__ u, const float* __restrict__ reg,
    const float* __restrict__ w10, const float* __restrict__ b10,
    const float* __restrict__ w11, const float* __restrict__ b11,
    const float* __restrict__ w12, const float* __restrict__ b12,
    const float* __restrict__ w20, const float* __restrict__ b20,
    const float* __restrict__ w21, const float* __restrict__ b21,
    const float* __restrict__ w22, const float* __restrict__ b22,
    const float* __restrict__ w30, const float* __restrict__ b30,
    const float* __restrict__ w31, const float* __restrict__ b31,
    const float* __restrict__ w32, const float* __restrict__ b32,
    float* __restrict__ out, int n)
{
    __shared__ float4 s4[ROWS_PB * 9];   // 9216 B u-tile
    __shared__ float  sreg[37];

    const int brow = blockIdx.x * ROWS_PB;

    // ---- stage 64-row u-tile via DMA: wave-uniform LDS base + lane*16 ----
    {
        const float4* __restrict__ g = reinterpret_cast<const float4*>(u + (size_t)brow * 36);
        const int wid  = threadIdx.x >> 6;
        const int lane = threadIdx.x & 63;
#pragma unroll
        for (int w = 0; w < 3; ++w) {
            const int base = w * TPB + wid * 64;   // f4 units, wave-uniform
            __builtin_amdgcn_global_load_lds(
                (const __attribute__((address_space(1))) void*)(g + base + lane),
                (__attribute__((address_space(3))) void*)(s4 + base),
                16, 0, 0);
        }
    }
    if (threadIdx.x < 37) sreg[threadIdx.x] = reg[threadIdx.x];
    asm volatile("s_waitcnt vmcnt(0)" ::: "memory");
    __syncthreads();

    const int rl = threadIdx.x / 3;          // row within tile, 0..63
    const int r  = threadIdx.x - 3 * rl;     // 0..2 -> output cols 12r..12r+11
    const int row = brow + rl;
    if (row >= n) return;

    // ---- 20-col window from LDS: W(k) = u[row, (12r+k) mod 36], k=-4..15 ----
    float w_[20];
#pragma unroll
    for (int t = 0; t < 5; ++t) {
        int idx = 3 * r + 8 + t;               // 8..18
        if (idx >= 9) idx -= 9;                // 0..9
        if (idx >= 9) idx -= 9;                // 0..8 (double wrap)
        const float4 v = s4[rl * 9 + idx];
        w_[4*t+0] = v.x; w_[4*t+1] = v.y; w_[4*t+2] = v.z; w_[4*t+3] = v.w;
    }
#define W(k) w_[(k) + 4]

    const f2 r02 = splat2(sreg[0]);
    const float* rb = sreg + 12 * r;          // LDS, broadcast reads

    f2 c0[2], c1[2], c2[2];   // pair P covers jj = 2P, 2P+1

    // ---- phase 1: MLP1 -> c0 ----
#pragma unroll
    for (int P = 0; P < 2; ++P) {
        const int q = 6 * P;
        f2 a0, a1, a2;
        mlp_a2(mk2(W(q - 2), W(q + 1)), mk2(W(q), W(q + 3)), mk2(W(q + 1), W(q + 4)),
               w10, b10, w11, b11, w12, b12, a0, a1, a2);
        const f2 ua = mk2(W(q - 1), W(q + 2));
        const f2 ub = mk2(W(q + 2), W(q + 5));
        const f2 rv = mk2(rb[q + 1], rb[q + 4]);
        const f2 uv = mk2(W(q), W(q + 3));
        c0[P] = fma2(uv, rv, r02) + fma2(a2, ub, fma2(a1, ua, a0));
    }
    // ---- phase 2: MLP2 -> c1 ----
#pragma unroll
    for (int P = 0; P < 2; ++P) {
        const int q = 6 * P;
        f2 a0, a1, a2;
        mlp_a2(mk2(W(q), W(q + 3)), mk2(W(q + 1), W(q + 4)), mk2(W(q + 3), W(q + 6)),
               w20, b20, w21, b21, w22, b22, a0, a1, a2);
        const f2 ua = mk2(W(q - 1), W(q + 2));
        const f2 ub = mk2(W(q + 2), W(q + 5));
        const f2 rv = mk2(rb[q + 2], rb[q + 5]);
        const f2 uv = mk2(W(q + 1), W(q + 4));
        c1[P] = fma2(uv, rv, r02) + fma2(a2, ub, fma2(a1, ua, a0));
    }
    // ---- phase 3: MLP3 -> c2 ----
#pragma unroll
    for (int P = 0; P < 2; ++P) {
        const int q = 6 * P;
        f2 d0, d1;
        mlp_b2(mk2(W(q), W(q + 3)), mk2(W(q + 1), W(q + 4)),
               mk2(W(q + 3), W(q + 6)), mk2(W(q + 4), W(q + 7)),
               w30, b30, w31, b31, w32, b32, d0, d1);
        const f2 ub = mk2(W(q + 2), W(q + 5));
        const f2 rv = mk2(rb[q + 3], rb[q + 6]);
        c2[P] = fma2(ub, rv, r02) + fma2(d1, ub, d0);
    }
#undef W

    // ---- store 12 contiguous cols at out[row, 12r..12r+11] — NONTEMPORAL:
    // out is write-once-never-read; don't let it evict u from L2/L3.
    fv4* __restrict__ o4 = reinterpret_cast<fv4*>(out + (size_t)row * 36 + 12 * r);
    __builtin_nontemporal_store(mk4(c0[0].x, c1[0].x, c2[0].x, c0[0].y), o4 + 0);
    __builtin_nontemporal_store(mk4(c1[0].y, c2[0].y, c0[1].x, c1[1].x), o4 + 1);
    __builtin_nontemporal_store(mk4(c2[1].x, c0[1].y, c1[1].y, c2[1].y), o4 + 2);
}

extern "C" void kernel_launch(void* const* d_in, const int* in_sizes, int n_in,
                              void* d_out, int out_size, void* d_ws, size_t ws_size,
                              hipStream_t stream)
{
    const float* u   = (const float*)d_in[1];
    const float* reg = (const float*)d_in[2];
    const float* w10 = (const float*)d_in[3];
    const float* b10 = (const float*)d_in[4];
    const float* w11 = (const float*)d_in[5];
    const float* b11 = (const float*)d_in[6];
    const float* w12 = (const float*)d_in[7];
    const float* b12 = (const float*)d_in[8];
    const float* w20 = (const float*)d_in[9];
    const float* b20 = (const float*)d_in[10];
    const float* w21 = (const float*)d_in[11];
    const float* b21 = (const float*)d_in[12];
    const float* w22 = (const float*)d_in[13];
    const float* b22 = (const float*)d_in[14];
    const float* w30 = (const float*)d_in[15];
    const float* b30 = (const float*)d_in[16];
    const float* w31 = (const float*)d_in[17];
    const float* b31 = (const float*)d_in[18];
    const float* w32 = (const float*)d_in[19];
    const float* b32 = (const float*)d_in[20];
    float* out = (float*)d_out;

    const int n = in_sizes[1] / 36;            // 1,000,000 rows; 64 | n exactly
    const int grid = (n + ROWS_PB - 1) / ROWS_PB;   // 15625 full tiles

    hipLaunchKernelGGL(mixmodel_kernel, dim3(grid), dim3(TPB), 0, stream,
                       u, reg, w10, b10, w11, b11, w12, b12,
                       w20, b20, w21, b21, w22, b22,
                       w30, b30, w31, b31, w32, b32, out, n);
}

// Round 17
// 65.176 us; speedup vs baseline: 1.1997x; 1.0012x over previous
//
#include <hip/hip_runtime.h>

// ---------------------------------------------------------------------------
// MixModel R17: row-pair packed-f32. Thread (rp,s) = rows {2rp,2rp+1},
// cols 6s..6s+5 (j = 2s,2s+1). pk pair-axis = adjacent ROWS, so every MLP
// operand pair is (u[rA][c], u[rB][c]) = LDS dwords 36 apart -> one
// ds_read2_b32 (compiler-fused). Kills w_[20] staging + ~40-60 mk2/v_mov
// repack instrs of R16. Staging/DMA/NT-stores/geometry = R16.
// Ladder: R10 LDS-DMA 71.1 | R16 +NT stores 65.3 (best; NT won via L2
//   depollution: FETCH unchanged 70MB, WRITE rose to 204MB) | others worse.
// Tripwires: VGPR>64 or WRITE>>210MB (spill/write-amp) -> revert to R16.
// ---------------------------------------------------------------------------

typedef float f2 __attribute__((ext_vector_type(2)));

__device__ __forceinline__ f2 splat2(float x) { f2 v; v.x = x; v.y = x; return v; }
__device__ __forceinline__ f2 mk2(float a, float b) { f2 v; v.x = a; v.y = b; return v; }
__device__ __forceinline__ f2 fma2(f2 a, f2 b, f2 c) { return __builtin_elementwise_fma(a, b, c); }
__device__ __forceinline__ f2 relu2(f2 a) { return __builtin_elementwise_max(a, splat2(0.0f)); }

// Packed MLP 3->3->6->3 (pair-axis = 2 rows).
__device__ __forceinline__ void mlp_a2(f2 x0, f2 x1, f2 x2,
                                       const float* __restrict__ w0, const float* __restrict__ b0,
                                       const float* __restrict__ w1, const float* __restrict__ b1,
                                       const float* __restrict__ w2, const float* __restrict__ b2,
                                       f2& o0, f2& o1, f2& o2)
{
    f2 h0[3];
#pragma unroll
    for (int q = 0; q < 3; ++q) {
        f2 a = fma2(x0, splat2(w0[q*3+0]), splat2(b0[q]));
        a = fma2(x1, splat2(w0[q*3+1]), a);
        a = fma2(x2, splat2(w0[q*3+2]), a);
        h0[q] = relu2(a);
    }
    f2 h1[6];
#pragma unroll
    for (int q = 0; q < 6; ++q) {
        f2 a = fma2(h0[0], splat2(w1[q*3+0]), splat2(b1[q]));
        a = fma2(h0[1], splat2(w1[q*3+1]), a);
        a = fma2(h0[2], splat2(w1[q*3+2]), a);
        h1[q] = relu2(a);
    }
    f2 t[3];
#pragma unroll
    for (int q = 0; q < 3; ++q) {
        f2 a = fma2(h1[0], splat2(w2[q*6+0]), splat2(b2[q]));
#pragma unroll
        for (int i = 1; i < 6; ++i) a = fma2(h1[i], splat2(w2[q*6+i]), a);
        t[q] = a;
    }
    o0 = t[0]; o1 = t[1]; o2 = t[2];
}

// Packed MLP 4->4->6->2 (pair-axis = 2 rows).
__device__ __forceinline__ void mlp_b2(f2 x0, f2 x1, f2 x2, f2 x3,
                                       const float* __restrict__ w0, const float* __restrict__ b0,
                                       const float* __restrict__ w1, const float* __restrict__ b1,
                                       const float* __restrict__ w2, const float* __restrict__ b2,
                                       f2& o0, f2& o1)
{
    f2 h0[4];
#pragma unroll
    for (int q = 0; q < 4; ++q) {
        f2 a = fma2(x0, splat2(w0[q*4+0]), splat2(b0[q]));
        a = fma2(x1, splat2(w0[q*4+1]), a);
        a = fma2(x2, splat2(w0[q*4+2]), a);
        a = fma2(x3, splat2(w0[q*4+3]), a);
        h0[q] = relu2(a);
    }
    f2 h1[6];
#pragma unroll
    for (int q = 0; q < 6; ++q) {
        f2 a = fma2(h0[0], splat2(w1[q*4+0]), splat2(b1[q]));
        a = fma2(h0[1], splat2(w1[q*4+1]), a);
        a = fma2(h0[2], splat2(w1[q*4+2]), a);
        a = fma2(h0[3], splat2(w1[q*4+3]), a);
        h1[q] = relu2(a);
    }
    f2 t[2];
#pragma unroll
    for (int q = 0; q < 2; ++q) {
        f2 a = fma2(h1[0], splat2(w2[q*6+0]), splat2(b2[q]));
#pragma unroll
        for (int i = 1; i < 6; ++i) a = fma2(h1[i], splat2(w2[q*6+i]), a);
        t[q] = a;
    }
    o0 = t[0]; o1 = t[1];
}

#define ROWS_PB 64
#define TPB 192   // 3 waves; 64 rows = 32 row-pairs x 6 col-segments = 192

__global__ __launch_bounds__(TPB) void mixmodel_kernel(
    const float* __restrict__ u, const float* __restrict__ reg,
    const float* __restrict__ w10, const float* __restrict__ b10,
    const float* __restrict__ w11, const float* __restrict__ b11,
    const float* __restrict__ w12, const float* __restrict__ b12,
    const float* __restrict__ w20, const float* __restrict__ b20,
    const float* __restrict__ w21, const float* __restrict__ b21,
    const float* __restrict__ w22, const float* __restrict__ b22,
    const float* __restrict__ w30, const float* __restrict__ b30,
    const float* __restrict__ w31, const float* __restrict__ b31,
    const float* __restrict__ w32, const float* __restrict__ b32,
    float* __restrict__ out, int n)
{
    __shared__ float4 s4[ROWS_PB * 9];   // 9216 B u-tile, row-major [64][36]f
    __shared__ float  sreg[37];

    const int brow = blockIdx.x * ROWS_PB;

    // ---- stage 64-row u-tile via DMA (identical to R16) ----
    {
        const float4* __restrict__ g = reinterpret_cast<const float4*>(u + (size_t)brow * 36);
        const int wid  = threadIdx.x >> 6;
        const int lane = threadIdx.x & 63;
#pragma unroll
        for (int w = 0; w < 3; ++w) {
            const int base = w * TPB + wid * 64;   // f4 units, wave-uniform
            __builtin_amdgcn_global_load_lds(
                (const __attribute__((address_space(1))) void*)(g + base + lane),
                (__attribute__((address_space(3))) void*)(s4 + base),
                16, 0, 0);
        }
    }
    if (threadIdx.x < 37) sreg[threadIdx.x] = reg[threadIdx.x];
    asm volatile("s_waitcnt vmcnt(0)" ::: "memory");
    __syncthreads();

    const int t  = threadIdx.x;
    const int rp = t / 6;              // row-pair 0..31 (rows 2rp, 2rp+1)
    const int s  = t - 6 * rp;         // col-segment 0..5 (cols 6s..6s+5)

    const float* sf = reinterpret_cast<const float*>(s4);
    const int va  = rp * 72 + 6 * s;               // dword idx (row 2rp, col 6s)
    const int vaP = va - 2 + (s == 0 ? 36 : 0);    // pre-edge base (k=-2,-1)
    const int vaT = va + (s == 5 ? -36 : 0);       // tail base (k=6,7)

    // ---- pairs P[k+2] = (u[rA][(6s+k)%36], u[rB][same]), k = -2..7 ----
    // each is 2 LDS dwords 36 apart -> ds_read2_b32
    f2 P[10];
#pragma unroll
    for (int k = 0; k < 2; ++k) { P[k].x = sf[vaP + k];     P[k].y = sf[vaP + k + 36]; }
#pragma unroll
    for (int k = 0; k < 6; ++k) { P[k + 2].x = sf[va + k];  P[k + 2].y = sf[va + k + 36]; }
#pragma unroll
    for (int k = 6; k < 8; ++k) { P[k + 2].x = sf[vaT + k]; P[k + 2].y = sf[vaT + k + 36]; }

    const f2 r02 = splat2(sreg[0]);
    const float* rb = sreg + 6 * s;    // rb[1..6] = reg[6s+1 .. 6s+6]

    f2 c_[6];                          // cols 6s+0..5, pair = (rowA, rowB)

    // ---- phase 1: MLP1 -> cols 3j+0 ----
#pragma unroll
    for (int J = 0; J < 2; ++J) {
        const int b = 3 * J;           // k-base for j = 2s+J
        f2 a0, a1, a2;
        // x = { W(3j-2)=P[b], W(3j)=P[b+2], W(3j+1)=P[b+3] }
        mlp_a2(P[b], P[b + 2], P[b + 3], w10, b10, w11, b11, w12, b12, a0, a1, a2);
        // ua = W(3j-1)=P[b+1], ub = W(3j+2)=P[b+4], uv = W(3j)=P[b+2]
        c_[3*J + 0] = fma2(P[b + 2], splat2(rb[b + 1]), r02)
                    + fma2(a2, P[b + 4], fma2(a1, P[b + 1], a0));
    }
    // ---- phase 2: MLP2 -> cols 3j+1 ----
#pragma unroll
    for (int J = 0; J < 2; ++J) {
        const int b = 3 * J;
        f2 a0, a1, a2;
        // x = { W(3j)=P[b+2], W(3j+1)=P[b+3], W(3j+3)=P[b+5] }
        mlp_a2(P[b + 2], P[b + 3], P[b + 5], w20, b20, w21, b21, w22, b22, a0, a1, a2);
        c_[3*J + 1] = fma2(P[b + 3], splat2(rb[b + 2]), r02)
                    + fma2(a2, P[b + 4], fma2(a1, P[b + 1], a0));
    }
    // ---- phase 3: MLP3 -> cols 3j+2 ----
#pragma unroll
    for (int J = 0; J < 2; ++J) {
        const int b = 3 * J;
        f2 d0, d1;
        // x = { W(3j)=P[b+2], W(3j+1)=P[b+3], W(3j+3)=P[b+5], W(3j+4)=P[b+6] }
        mlp_b2(P[b + 2], P[b + 3], P[b + 5], P[b + 6], w30, b30, w31, b31, w32, b32, d0, d1);
        // ub = W(3j+2) = P[b+4]
        c_[3*J + 2] = fma2(P[b + 4], splat2(rb[b + 3]), r02)
                    + fma2(d1, P[b + 4], d0);
    }

    // ---- stores: rowA/rowB x 6 cols, 3x 8B NT each (lane sextet = 288B) ----
    float* oA = out + (size_t)(brow + 2 * rp) * 36 + 6 * s;
    float* oB = oA + 36;
    __builtin_nontemporal_store(mk2(c_[0].x, c_[1].x), (f2*)(oA + 0));
    __builtin_nontemporal_store(mk2(c_[2].x, c_[3].x), (f2*)(oA + 2));
    __builtin_nontemporal_store(mk2(c_[4].x, c_[5].x), (f2*)(oA + 4));
    __builtin_nontemporal_store(mk2(c_[0].y, c_[1].y), (f2*)(oB + 0));
    __builtin_nontemporal_store(mk2(c_[2].y, c_[3].y), (f2*)(oB + 2));
    __builtin_nontemporal_store(mk2(c_[4].y, c_[5].y), (f2*)(oB + 4));
}

extern "C" void kernel_launch(void* const* d_in, const int* in_sizes, int n_in,
                              void* d_out, int out_size, void* d_ws, size_t ws_size,
                              hipStream_t stream)
{
    const float* u   = (const float*)d_in[1];
    const float* reg = (const float*)d_in[2];
    const float* w10 = (const float*)d_in[3];
    const float* b10 = (const float*)d_in[4];
    const float* w11 = (const float*)d_in[5];
    const float* b11 = (const float*)d_in[6];
    const float* w12 = (const float*)d_in[7];
    const float* b12 = (const float*)d_in[8];
    const float* w20 = (const float*)d_in[9];
    const float* b20 = (const float*)d_in[10];
    const float* w21 = (const float*)d_in[11];
    const float* b21 = (const float*)d_in[12];
    const float* w22 = (const float*)d_in[13];
    const float* b22 = (const float*)d_in[14];
    const float* w30 = (const float*)d_in[15];
    const float* b30 = (const float*)d_in[16];
    const float* w31 = (const float*)d_in[17];
    const float* b31 = (const float*)d_in[18];
    const float* w32 = (const float*)d_in[19];
    const float* b32 = (const float*)d_in[20];
    float* out = (float*)d_out;

    const int n = in_sizes[1] / 36;            // 1,000,000 rows; 64 | n exactly
    const int grid = (n + ROWS_PB - 1) / ROWS_PB;   // 15625 full tiles

    hipLaunchKernelGGL(mixmodel_kernel, dim3(grid), dim3(TPB), 0, stream,
                       u, reg, w10, b10, w11, b11, w12, b12,
                       w20, b20, w21, b21, w22, b22,
                       w30, b30, w31, b31, w32, b32, out, n);
}

// Round 18
// 62.045 us; speedup vs baseline: 1.2603x; 1.0505x over previous
//
#include <hip/hip_runtime.h>

// ---------------------------------------------------------------------------
// MixModel R18 = R17 (row-pair pk-f32, LDS-DMA staged) + LDS output
// round-trip so NT stores are lane-contiguous (no write amplification).
// Ladder: R10 71.1 | R16 +NT 65.3 | R17 row-pair pk 65.2 (VALU 38->32%,
//   neutral -> not VALU-bound; hbm_bytes 283MB/65us = 4.3TB/s ~ 70% ceiling,
//   WRITE 213MB vs 140.6 ideal = NT 16B-scattered partial-line amplification)
// R18: after compute the input tile in LDS is dead -> write results there
//   (6x ds_write_b64), barrier, thread t re-reads flat float4 {t,t+192,t+384}
//   and NT-stores to the block's contiguous 9216B out region: 1024B/instr,
//   full 64B lines. Keep NT for L2 depollution (the R16 win).
// Tripwires: WRITE >> 141MB (amp back) or VGPR > 64 (spill) -> revert.
// ---------------------------------------------------------------------------

typedef float f2 __attribute__((ext_vector_type(2)));
typedef float fv4 __attribute__((ext_vector_type(4)));

__device__ __forceinline__ f2 splat2(float x) { f2 v; v.x = x; v.y = x; return v; }
__device__ __forceinline__ f2 mk2(float a, float b) { f2 v; v.x = a; v.y = b; return v; }
__device__ __forceinline__ f2 fma2(f2 a, f2 b, f2 c) { return __builtin_elementwise_fma(a, b, c); }
__device__ __forceinline__ f2 relu2(f2 a) { return __builtin_elementwise_max(a, splat2(0.0f)); }

// Packed MLP 3->3->6->3 (pair-axis = 2 rows).
__device__ __forceinline__ void mlp_a2(f2 x0, f2 x1, f2 x2,
                                       const float* __restrict__ w0, const float* __restrict__ b0,
                                       const float* __restrict__ w1, const float* __restrict__ b1,
                                       const float* __restrict__ w2, const float* __restrict__ b2,
                                       f2& o0, f2& o1, f2& o2)
{
    f2 h0[3];
#pragma unroll
    for (int q = 0; q < 3; ++q) {
        f2 a = fma2(x0, splat2(w0[q*3+0]), splat2(b0[q]));
        a = fma2(x1, splat2(w0[q*3+1]), a);
        a = fma2(x2, splat2(w0[q*3+2]), a);
        h0[q] = relu2(a);
    }
    f2 h1[6];
#pragma unroll
    for (int q = 0; q < 6; ++q) {
        f2 a = fma2(h0[0], splat2(w1[q*3+0]), splat2(b1[q]));
        a = fma2(h0[1], splat2(w1[q*3+1]), a);
        a = fma2(h0[2], splat2(w1[q*3+2]), a);
        h1[q] = relu2(a);
    }
    f2 t[3];
#pragma unroll
    for (int q = 0; q < 3; ++q) {
        f2 a = fma2(h1[0], splat2(w2[q*6+0]), splat2(b2[q]));
#pragma unroll
        for (int i = 1; i < 6; ++i) a = fma2(h1[i], splat2(w2[q*6+i]), a);
        t[q] = a;
    }
    o0 = t[0]; o1 = t[1]; o2 = t[2];
}

// Packed MLP 4->4->6->2 (pair-axis = 2 rows).
__device__ __forceinline__ void mlp_b2(f2 x0, f2 x1, f2 x2, f2 x3,
                                       const float* __restrict__ w0, const float* __restrict__ b0,
                                       const float* __restrict__ w1, const float* __restrict__ b1,
                                       const float* __restrict__ w2, const float* __restrict__ b2,
                                       f2& o0, f2& o1)
{
    f2 h0[4];
#pragma unroll
    for (int q = 0; q < 4; ++q) {
        f2 a = fma2(x0, splat2(w0[q*4+0]), splat2(b0[q]));
        a = fma2(x1, splat2(w0[q*4+1]), a);
        a = fma2(x2, splat2(w0[q*4+2]), a);
        a = fma2(x3, splat2(w0[q*4+3]), a);
        h0[q] = relu2(a);
    }
    f2 h1[6];
#pragma unroll
    for (int q = 0; q < 6; ++q) {
        f2 a = fma2(h0[0], splat2(w1[q*4+0]), splat2(b1[q]));
        a = fma2(h0[1], splat2(w1[q*4+1]), a);
        a = fma2(h0[2], splat2(w1[q*4+2]), a);
        a = fma2(h0[3], splat2(w1[q*4+3]), a);
        h1[q] = relu2(a);
    }
    f2 t[2];
#pragma unroll
    for (int q = 0; q < 2; ++q) {
        f2 a = fma2(h1[0], splat2(w2[q*6+0]), splat2(b2[q]));
#pragma unroll
        for (int i = 1; i < 6; ++i) a = fma2(h1[i], splat2(w2[q*6+i]), a);
        t[q] = a;
    }
    o0 = t[0]; o1 = t[1];
}

#define ROWS_PB 64
#define TPB 192   // 3 waves; 64 rows = 32 row-pairs x 6 col-segments = 192

__global__ __launch_bounds__(TPB) void mixmodel_kernel(
    const float* __restrict__ u, const float* __restrict__ reg,
    const float* __restrict__ w10, const float* __restrict__ b10,
    const float* __restrict__ w11, const float* __restrict__ b11,
    const float* __restrict__ w12, const float* __restrict__ b12,
    const float* __restrict__ w20, const float* __restrict__ b20,
    const float* __restrict__ w21, const float* __restrict__ b21,
    const float* __restrict__ w22, const float* __restrict__ b22,
    const float* __restrict__ w30, const float* __restrict__ b30,
    const float* __restrict__ w31, const float* __restrict__ b31,
    const float* __restrict__ w32, const float* __restrict__ b32,
    float* __restrict__ out, int n)
{
    __shared__ float4 s4[ROWS_PB * 9];   // 9216 B tile: u in, results out
    __shared__ float  sreg[37];

    const int brow = blockIdx.x * ROWS_PB;

    // ---- stage 64-row u-tile via DMA (identical to R16/R17) ----
    {
        const float4* __restrict__ g = reinterpret_cast<const float4*>(u + (size_t)brow * 36);
        const int wid  = threadIdx.x >> 6;
        const int lane = threadIdx.x & 63;
#pragma unroll
        for (int w = 0; w < 3; ++w) {
            const int base = w * TPB + wid * 64;   // f4 units, wave-uniform
            __builtin_amdgcn_global_load_lds(
                (const __attribute__((address_space(1))) void*)(g + base + lane),
                (__attribute__((address_space(3))) void*)(s4 + base),
                16, 0, 0);
        }
    }
    if (threadIdx.x < 37) sreg[threadIdx.x] = reg[threadIdx.x];
    asm volatile("s_waitcnt vmcnt(0)" ::: "memory");
    __syncthreads();

    const int t  = threadIdx.x;
    const int rp = t / 6;              // row-pair 0..31 (rows 2rp, 2rp+1)
    const int s  = t - 6 * rp;         // col-segment 0..5 (cols 6s..6s+5)

    const float* sf = reinterpret_cast<const float*>(s4);
    const int va  = rp * 72 + 6 * s;               // dword idx (row 2rp, col 6s)
    const int vaP = va - 2 + (s == 0 ? 36 : 0);    // pre-edge base (k=-2,-1)
    const int vaT = va + (s == 5 ? -36 : 0);       // tail base (k=6,7)

    // ---- pairs P[k+2] = (u[rA][(6s+k)%36], u[rB][same]), k = -2..7 ----
    f2 P[10];
#pragma unroll
    for (int k = 0; k < 2; ++k) { P[k].x = sf[vaP + k];     P[k].y = sf[vaP + k + 36]; }
#pragma unroll
    for (int k = 0; k < 6; ++k) { P[k + 2].x = sf[va + k];  P[k + 2].y = sf[va + k + 36]; }
#pragma unroll
    for (int k = 6; k < 8; ++k) { P[k + 2].x = sf[vaT + k]; P[k + 2].y = sf[vaT + k + 36]; }

    const f2 r02 = splat2(sreg[0]);
    const float* rb = sreg + 6 * s;    // rb[1..6] = reg[6s+1 .. 6s+6]

    f2 c_[6];                          // cols 6s+0..5, pair = (rowA, rowB)

    // ---- phase 1: MLP1 -> cols 3j+0 ----
#pragma unroll
    for (int J = 0; J < 2; ++J) {
        const int b = 3 * J;           // k-base for j = 2s+J
        f2 a0, a1, a2;
        mlp_a2(P[b], P[b + 2], P[b + 3], w10, b10, w11, b11, w12, b12, a0, a1, a2);
        c_[3*J + 0] = fma2(P[b + 2], splat2(rb[b + 1]), r02)
                    + fma2(a2, P[b + 4], fma2(a1, P[b + 1], a0));
    }
    // ---- phase 2: MLP2 -> cols 3j+1 ----
#pragma unroll
    for (int J = 0; J < 2; ++J) {
        const int b = 3 * J;
        f2 a0, a1, a2;
        mlp_a2(P[b + 2], P[b + 3], P[b + 5], w20, b20, w21, b21, w22, b22, a0, a1, a2);
        c_[3*J + 1] = fma2(P[b + 3], splat2(rb[b + 2]), r02)
                    + fma2(a2, P[b + 4], fma2(a1, P[b + 1], a0));
    }
    // ---- phase 3: MLP3 -> cols 3j+2 ----
#pragma unroll
    for (int J = 0; J < 2; ++J) {
        const int b = 3 * J;
        f2 d0, d1;
        mlp_b2(P[b + 2], P[b + 3], P[b + 5], P[b + 6], w30, b30, w31, b31, w32, b32, d0, d1);
        c_[3*J + 2] = fma2(P[b + 4], splat2(rb[b + 3]), r02)
                    + fma2(d1, P[b + 4], d0);
    }

    // ---- all threads done READING s4 -> reuse it as the output tile ----
    __syncthreads();
    {
        float* sfo = reinterpret_cast<float*>(s4);   // row-major [64][36]
        f2* wA = reinterpret_cast<f2*>(sfo + va);        // va even -> 8B aligned
        f2* wB = reinterpret_cast<f2*>(sfo + va + 36);
        wA[0] = mk2(c_[0].x, c_[1].x);
        wA[1] = mk2(c_[2].x, c_[3].x);
        wA[2] = mk2(c_[4].x, c_[5].x);
        wB[0] = mk2(c_[0].y, c_[1].y);
        wB[1] = mk2(c_[2].y, c_[3].y);
        wB[2] = mk2(c_[4].y, c_[5].y);
    }
    __syncthreads();

    // ---- flat, lane-contiguous NT stores: 3 x 1024B per wave instruction ----
    {
        fv4* __restrict__ ob = reinterpret_cast<fv4*>(out + (size_t)brow * 36);
        const fv4* sv = reinterpret_cast<const fv4*>(s4);
#pragma unroll
        for (int k = 0; k < 3; ++k) {
            const int idx = t + k * TPB;          // 0..575, lane-contiguous
            __builtin_nontemporal_store(sv[idx], ob + idx);
        }
    }
}

extern "C" void kernel_launch(void* const* d_in, const int* in_sizes, int n_in,
                              void* d_out, int out_size, void* d_ws, size_t ws_size,
                              hipStream_t stream)
{
    const float* u   = (const float*)d_in[1];
    const float* reg = (const float*)d_in[2];
    const float* w10 = (const float*)d_in[3];
    const float* b10 = (const float*)d_in[4];
    const float* w11 = (const float*)d_in[5];
    const float* b11 = (const float*)d_in[6];
    const float* w12 = (const float*)d_in[7];
    const float* b12 = (const float*)d_in[8];
    const float* w20 = (const float*)d_in[9];
    const float* b20 = (const float*)d_in[10];
    const float* w21 = (const float*)d_in[11];
    const float* b21 = (const float*)d_in[12];
    const float* w22 = (const float*)d_in[13];
    const float* b22 = (const float*)d_in[14];
    const float* w30 = (const float*)d_in[15];
    const float* b30 = (const float*)d_in[16];
    const float* w31 = (const float*)d_in[17];
    const float* b31 = (const float*)d_in[18];
    const float* w32 = (const float*)d_in[19];
    const float* b32 = (const float*)d_in[20];
    float* out = (float*)d_out;

    const int n = in_sizes[1] / 36;            // 1,000,000 rows; 64 | n exactly
    const int grid = (n + ROWS_PB - 1) / ROWS_PB;   // 15625 full tiles

    hipLaunchKernelGGL(mixmodel_kernel, dim3(grid), dim3(TPB), 0, stream,
                       u, reg, w10, b10, w11, b11, w12, b12,
                       w20, b20, w21, b21, w22, b22,
                       w30, b30, w31, b31, w32, b32, out, n);
}

// Round 19
// 59.804 us; speedup vs baseline: 1.3075x; 1.0375x over previous
//
#include <hip/hip_runtime.h>

// ---------------------------------------------------------------------------
// MixModel R19 = R18 with a SEPARATE LDS output buffer -> 2 barriers not 3.
// Ladder: R10 71.1 | R16 +NT 65.3 | R17 row-pair pk 65.2 | R18 +LDS-out
//   round-trip 62.0 (WRITE back to 140.6MB exact — NT amp killed).
// R18 tail was {bar2: done-reading-s4 -> ds_write results -> bar3 -> flat NT}.
// bar2 only guarded the in-place reuse of s4 (neighbor threads read wrapped
// cols of my rows). Separate obuf kills the WAR hazard -> compute ->
// ds_write obuf -> ONE barrier -> flat NT store. LDS 18.6KB (8 blocks/CU cap,
// above measured-resident ~4). Everything else identical to R18.
// Tripwires: WRITE >> 141MB or VGPR > 64 -> revert to R18.
// ---------------------------------------------------------------------------

typedef float f2 __attribute__((ext_vector_type(2)));
typedef float fv4 __attribute__((ext_vector_type(4)));

__device__ __forceinline__ f2 splat2(float x) { f2 v; v.x = x; v.y = x; return v; }
__device__ __forceinline__ f2 mk2(float a, float b) { f2 v; v.x = a; v.y = b; return v; }
__device__ __forceinline__ f2 fma2(f2 a, f2 b, f2 c) { return __builtin_elementwise_fma(a, b, c); }
__device__ __forceinline__ f2 relu2(f2 a) { return __builtin_elementwise_max(a, splat2(0.0f)); }

// Packed MLP 3->3->6->3 (pair-axis = 2 rows).
__device__ __forceinline__ void mlp_a2(f2 x0, f2 x1, f2 x2,
                                       const float* __restrict__ w0, const float* __restrict__ b0,
                                       const float* __restrict__ w1, const float* __restrict__ b1,
                                       const float* __restrict__ w2, const float* __restrict__ b2,
                                       f2& o0, f2& o1, f2& o2)
{
    f2 h0[3];
#pragma unroll
    for (int q = 0; q < 3; ++q) {
        f2 a = fma2(x0, splat2(w0[q*3+0]), splat2(b0[q]));
        a = fma2(x1, splat2(w0[q*3+1]), a);
        a = fma2(x2, splat2(w0[q*3+2]), a);
        h0[q] = relu2(a);
    }
    f2 h1[6];
#pragma unroll
    for (int q = 0; q < 6; ++q) {
        f2 a = fma2(h0[0], splat2(w1[q*3+0]), splat2(b1[q]));
        a = fma2(h0[1], splat2(w1[q*3+1]), a);
        a = fma2(h0[2], splat2(w1[q*3+2]), a);
        h1[q] = relu2(a);
    }
    f2 t[3];
#pragma unroll
    for (int q = 0; q < 3; ++q) {
        f2 a = fma2(h1[0], splat2(w2[q*6+0]), splat2(b2[q]));
#pragma unroll
        for (int i = 1; i < 6; ++i) a = fma2(h1[i], splat2(w2[q*6+i]), a);
        t[q] = a;
    }
    o0 = t[0]; o1 = t[1]; o2 = t[2];
}

// Packed MLP 4->4->6->2 (pair-axis = 2 rows).
__device__ __forceinline__ void mlp_b2(f2 x0, f2 x1, f2 x2, f2 x3,
                                       const float* __restrict__ w0, const float* __restrict__ b0,
                                       const float* __restrict__ w1, const float* __restrict__ b1,
                                       const float* __restrict__ w2, const float* __restrict__ b2,
                                       f2& o0, f2& o1)
{
    f2 h0[4];
#pragma unroll
    for (int q = 0; q < 4; ++q) {
        f2 a = fma2(x0, splat2(w0[q*4+0]), splat2(b0[q]));
        a = fma2(x1, splat2(w0[q*4+1]), a);
        a = fma2(x2, splat2(w0[q*4+2]), a);
        a = fma2(x3, splat2(w0[q*4+3]), a);
        h0[q] = relu2(a);
    }
    f2 h1[6];
#pragma unroll
    for (int q = 0; q < 6; ++q) {
        f2 a = fma2(h0[0], splat2(w1[q*4+0]), splat2(b1[q]));
        a = fma2(h0[1], splat2(w1[q*4+1]), a);
        a = fma2(h0[2], splat2(w1[q*4+2]), a);
        a = fma2(h0[3], splat2(w1[q*4+3]), a);
        h1[q] = relu2(a);
    }
    f2 t[2];
#pragma unroll
    for (int q = 0; q < 2; ++q) {
        f2 a = fma2(h1[0], splat2(w2[q*6+0]), splat2(b2[q]));
#pragma unroll
        for (int i = 1; i < 6; ++i) a = fma2(h1[i], splat2(w2[q*6+i]), a);
        t[q] = a;
    }
    o0 = t[0]; o1 = t[1];
}

#define ROWS_PB 64
#define TPB 192   // 3 waves; 64 rows = 32 row-pairs x 6 col-segments = 192

__global__ __launch_bounds__(TPB) void mixmodel_kernel(
    const float* __restrict__ u, const float* __restrict__ reg,
    const float* __restrict__ w10, const float* __restrict__ b10,
    const float* __restrict__ w11, const float* __restrict__ b11,
    const float* __restrict__ w12, const float* __restrict__ b12,
    const float* __restrict__ w20, const float* __restrict__ b20,
    const float* __restrict__ w21, const float* __restrict__ b21,
    const float* __restrict__ w22, const float* __restrict__ b22,
    const float* __restrict__ w30, const float* __restrict__ b30,
    const float* __restrict__ w31, const float* __restrict__ b31,
    const float* __restrict__ w32, const float* __restrict__ b32,
    float* __restrict__ out, int n)
{
    __shared__ float4 s4[ROWS_PB * 9];    // 9216 B input u-tile
    __shared__ float4 o4b[ROWS_PB * 9];   // 9216 B output tile (separate!)
    __shared__ float  sreg[37];

    const int brow = blockIdx.x * ROWS_PB;

    // ---- stage 64-row u-tile via DMA (identical to R16/R17/R18) ----
    {
        const float4* __restrict__ g = reinterpret_cast<const float4*>(u + (size_t)brow * 36);
        const int wid  = threadIdx.x >> 6;
        const int lane = threadIdx.x & 63;
#pragma unroll
        for (int w = 0; w < 3; ++w) {
            const int base = w * TPB + wid * 64;   // f4 units, wave-uniform
            __builtin_amdgcn_global_load_lds(
                (const __attribute__((address_space(1))) void*)(g + base + lane),
                (__attribute__((address_space(3))) void*)(s4 + base),
                16, 0, 0);
        }
    }
    if (threadIdx.x < 37) sreg[threadIdx.x] = reg[threadIdx.x];
    asm volatile("s_waitcnt vmcnt(0)" ::: "memory");
    __syncthreads();                      // barrier 1: tile ready

    const int t  = threadIdx.x;
    const int rp = t / 6;              // row-pair 0..31 (rows 2rp, 2rp+1)
    const int s  = t - 6 * rp;         // col-segment 0..5 (cols 6s..6s+5)

    const float* sf = reinterpret_cast<const float*>(s4);
    const int va  = rp * 72 + 6 * s;               // dword idx (row 2rp, col 6s)
    const int vaP = va - 2 + (s == 0 ? 36 : 0);    // pre-edge base (k=-2,-1)
    const int vaT = va + (s == 5 ? -36 : 0);       // tail base (k=6,7)

    // ---- pairs P[k+2] = (u[rA][(6s+k)%36], u[rB][same]), k = -2..7 ----
    f2 P[10];
#pragma unroll
    for (int k = 0; k < 2; ++k) { P[k].x = sf[vaP + k];     P[k].y = sf[vaP + k + 36]; }
#pragma unroll
    for (int k = 0; k < 6; ++k) { P[k + 2].x = sf[va + k];  P[k + 2].y = sf[va + k + 36]; }
#pragma unroll
    for (int k = 6; k < 8; ++k) { P[k + 2].x = sf[vaT + k]; P[k + 2].y = sf[vaT + k + 36]; }

    const f2 r02 = splat2(sreg[0]);
    const float* rb = sreg + 6 * s;    // rb[1..6] = reg[6s+1 .. 6s+6]

    f2 c_[6];                          // cols 6s+0..5, pair = (rowA, rowB)

    // ---- phase 1: MLP1 -> cols 3j+0 ----
#pragma unroll
    for (int J = 0; J < 2; ++J) {
        const int b = 3 * J;           // k-base for j = 2s+J
        f2 a0, a1, a2;
        mlp_a2(P[b], P[b + 2], P[b + 3], w10, b10, w11, b11, w12, b12, a0, a1, a2);
        c_[3*J + 0] = fma2(P[b + 2], splat2(rb[b + 1]), r02)
                    + fma2(a2, P[b + 4], fma2(a1, P[b + 1], a0));
    }
    // ---- phase 2: MLP2 -> cols 3j+1 ----
#pragma unroll
    for (int J = 0; J < 2; ++J) {
        const int b = 3 * J;
        f2 a0, a1, a2;
        mlp_a2(P[b + 2], P[b + 3], P[b + 5], w20, b20, w21, b21, w22, b22, a0, a1, a2);
        c_[3*J + 1] = fma2(P[b + 3], splat2(rb[b + 2]), r02)
                    + fma2(a2, P[b + 4], fma2(a1, P[b + 1], a0));
    }
    // ---- phase 3: MLP3 -> cols 3j+2 ----
#pragma unroll
    for (int J = 0; J < 2; ++J) {
        const int b = 3 * J;
        f2 d0, d1;
        mlp_b2(P[b + 2], P[b + 3], P[b + 5], P[b + 6], w30, b30, w31, b31, w32, b32, d0, d1);
        c_[3*J + 2] = fma2(P[b + 4], splat2(rb[b + 3]), r02)
                    + fma2(d1, P[b + 4], d0);
    }

    // ---- write results to the SEPARATE output tile (no WAR, no barrier) ----
    {
        float* sfo = reinterpret_cast<float*>(o4b);   // row-major [64][36]
        f2* wA = reinterpret_cast<f2*>(sfo + va);         // va even -> 8B aligned
        f2* wB = reinterpret_cast<f2*>(sfo + va + 36);
        wA[0] = mk2(c_[0].x, c_[1].x);
        wA[1] = mk2(c_[2].x, c_[3].x);
        wA[2] = mk2(c_[4].x, c_[5].x);
        wB[0] = mk2(c_[0].y, c_[1].y);
        wB[1] = mk2(c_[2].y, c_[3].y);
        wB[2] = mk2(c_[4].y, c_[5].y);
    }
    __syncthreads();                      // barrier 2: output tile complete

    // ---- flat, lane-contiguous NT stores: 3 x 1024B per wave instruction ----
    {
        fv4* __restrict__ ob = reinterpret_cast<fv4*>(out + (size_t)brow * 36);
        const fv4* sv = reinterpret_cast<const fv4*>(o4b);
#pragma unroll
        for (int k = 0; k < 3; ++k) {
            const int idx = t + k * TPB;          // 0..575, lane-contiguous
            __builtin_nontemporal_store(sv[idx], ob + idx);
        }
    }
}

extern "C" void kernel_launch(void* const* d_in, const int* in_sizes, int n_in,
                              void* d_out, int out_size, void* d_ws, size_t ws_size,
                              hipStream_t stream)
{
    const float* u   = (const float*)d_in[1];
    const float* reg = (const float*)d_in[2];
    const float* w10 = (const float*)d_in[3];
    const float* b10 = (const float*)d_in[4];
    const float* w11 = (const float*)d_in[5];
    const float* b11 = (const float*)d_in[6];
    const float* w12 = (const float*)d_in[7];
    const float* b12 = (const float*)d_in[8];
    const float* w20 = (const float*)d_in[9];
    const float* b20 = (const float*)d_in[10];
    const float* w21 = (const float*)d_in[11];
    const float* b21 = (const float*)d_in[12];
    const float* w22 = (const float*)d_in[13];
    const float* b22 = (const float*)d_in[14];
    const float* w30 = (const float*)d_in[15];
    const float* b30 = (const float*)d_in[16];
    const float* w31 = (const float*)d_in[17];
    const float* b31 = (const float*)d_in[18];
    const float* w32 = (const float*)d_in[19];
    const float* b32 = (const float*)d_in[20];
    float* out = (float*)d_out;

    const int n = in_sizes[1] / 36;            // 1,000,000 rows; 64 | n exactly
    const int grid = (n + ROWS_PB - 1) / ROWS_PB;   // 15625 full tiles

    hipLaunchKernelGGL(mixmodel_kernel, dim3(grid), dim3(TPB), 0, stream,
                       u, reg, w10, b10, w11, b11, w12, b12,
                       w20, b20, w21, b21, w22, b22,
                       w30, b30, w31, b31, w32, b32, out, n);
}